// Round 14
// baseline (747.222 us; speedup 1.0000x reference)
//
#include <hip/hip_runtime.h>
#include <math.h>

#define NN 50000
#define NE 800000
#define EMB 128
#define GH 64
#define BB 64
#define TT 200
#define HH 128
#define G4 512
#define IND 134
#define PM 128
#define PO 128

__device__ __forceinline__ float sigf(float x) { return 1.0f / (1.0f + __expf(-x)); }
__device__ __forceinline__ float tanhf_(float x) { return 1.0f - 2.0f / (__expf(2.0f * x) + 1.0f); }

// ---------------- CSR build ----------------
__global__ void hist_kernel(const int* __restrict__ ei, const float* __restrict__ ew,
                            int* __restrict__ cnt, float* __restrict__ degw) {
    int e = blockIdx.x * 256 + threadIdx.x;
    if (e >= NE) return;
    int d = ei[NE + e];
    atomicAdd(&cnt[d], 1);
    atomicAdd(&degw[d], ew[e]);
}

// scan1 + dinv fused (both depend only on hist)
__global__ __launch_bounds__(1024) void scan1_kernel(const int* __restrict__ cnt,
                                                     const float* __restrict__ degw,
                                                     float* __restrict__ dinv,
                                                     int* __restrict__ rs, int* __restrict__ partials) {
    __shared__ int s[1024];
    int gid = blockIdx.x * 1024 + threadIdx.x;
    int v = (gid < NN) ? cnt[gid] : 0;
    if (gid < NN) dinv[gid] = rsqrtf(degw[gid] + 1.0f);   // +1 self loop
    s[threadIdx.x] = v;
    __syncthreads();
    for (int off = 1; off < 1024; off <<= 1) {
        int add = (threadIdx.x >= (unsigned)off) ? s[threadIdx.x - off] : 0;
        __syncthreads();
        s[threadIdx.x] += add;
        __syncthreads();
    }
    if (gid < NN) rs[gid] = s[threadIdx.x] - v;  // exclusive
    if (threadIdx.x == 1023) partials[blockIdx.x] = s[1023];
}

// misc: block 0 = parallel scan of partials; blocks 1..34 = W1 transpose+reorder.
__global__ void misc_kernel(int* __restrict__ partials, int nblk,
                            const float* __restrict__ W1, float* __restrict__ w1t) {
    int blk = blockIdx.x;
    int tid = threadIdx.x;
    if (blk == 0) {
        __shared__ int s[64];
        int v = (tid < nblk) ? partials[tid] : 0;
        s[tid] = v;
        __syncthreads();
        for (int off = 1; off < 64; off <<= 1) {
            int add = (tid >= off) ? s[tid - off] : 0;
            __syncthreads();
            s[tid] += add;
            __syncthreads();
        }
        if (tid < nblk) partials[tid] = s[tid] - v;  // exclusive
    } else {
        int i = (blk - 1) * 256 + tid;
        if (i < 64 * 136) {
            int o = i / 136, j = i - o * 136;
            float v = 0.0f;
            if (j < 128) v = W1[(size_t)(j + 2) * GH + o];
            else if (j < 130) v = W1[(size_t)(j - 128) * GH + o];
            else if (j < 134) v = W1[(size_t)j * GH + o];
            w1t[i] = v;
        }
    }
}

// wcomb: fold gemm2 into pregemm via associativity.
__global__ __launch_bounds__(256) void wcomb_kernel(const float* __restrict__ w_ih_f,
                                                    const float* __restrict__ w_ih_b,
                                                    const float* __restrict__ W2,
                                                    const float* __restrict__ b2,
                                                    const float* __restrict__ b_ih_f,
                                                    const float* __restrict__ b_hh_f,
                                                    const float* __restrict__ b_ih_b,
                                                    const float* __restrict__ b_hh_b,
                                                    float* __restrict__ wcomb,
                                                    float* __restrict__ bcomb) {
    int bx = blockIdx.x, tid = threadIdx.x;
    int dir = bx >> 7, o0 = (bx & 127) * 4;
    const float* w_ih = dir ? w_ih_b : w_ih_f;
    __shared__ __align__(16) float w2s[GH][EMB];    // 32KB, [k][e]
    __shared__ __align__(16) float wihs[4][EMB];    // 2KB, [oo][e]
    __shared__ __align__(16) float b2s[EMB];
    for (int i = tid; i < GH * EMB / 4; i += 256)
        ((float4*)w2s)[i] = ((const float4*)W2)[i];
    for (int i = tid; i < 4 * EMB / 4; i += 256) {
        int oo = i >> 5, e4 = i & 31;
        ((float4*)wihs)[i] = *(const float4*)&w_ih[(size_t)(o0 + oo) * EMB + e4 * 4];
    }
    if (tid < 32) ((float4*)b2s)[tid] = ((const float4*)b2)[tid];
    __syncthreads();
    int oo = tid >> 6, k = tid & 63;
    float acc = 0.0f;
#pragma unroll 8
    for (int e4 = 0; e4 < 32; ++e4) {
        float4 a = *(const float4*)&wihs[oo][e4 * 4];
        float4 w = *(const float4*)&w2s[k][e4 * 4];
        acc += a.x * w.x + a.y * w.y + a.z * w.z + a.w * w.w;
    }
    wcomb[((size_t)dir * G4 + o0 + oo) * GH + k] = acc;
    if (tid < 4) {
        int o = o0 + tid;
        float s = dir ? (b_ih_b[o] + b_hh_b[o]) : (b_ih_f[o] + b_hh_f[o]);
        for (int e = 0; e < EMB; ++e) s += wihs[tid][e] * b2s[e];
        bcomb[dir * G4 + o] = s;
    }
}

__global__ __launch_bounds__(1024) void scan3_kernel(const int* __restrict__ partials,
                                                     int* __restrict__ rs, int* __restrict__ cursor) {
    int gid = blockIdx.x * 1024 + threadIdx.x;
    if (gid < NN) {
        int v = rs[gid] + partials[gid >> 10];
        rs[gid] = v;
        cursor[gid] = v;
    }
    if (gid == 0) rs[NN] = NE;
}

// fill: (src, weight) packed into int2
__global__ void fill_kernel(const int* __restrict__ ei, const float* __restrict__ ew,
                            const float* __restrict__ dinv, int* __restrict__ cursor,
                            int2* __restrict__ ssrcw) {
    int e = blockIdx.x * 256 + threadIdx.x;
    if (e >= NE) return;
    int s = ei[e], d = ei[NE + e];
    int pos = atomicAdd(&cursor[d], 1);
    ssrcw[pos] = make_int2(s, __float_as_int(ew[e] * dinv[s] * dinv[d]));
}

// ---------------- GCN layer 1 GEMM v2 (134 -> 64), register-tiled ----------------
__global__ __launch_bounds__(256) void gemm1_kernel(const float* __restrict__ coords,
                                                    const float* __restrict__ temporal,
                                                    const float* __restrict__ emb,
                                                    const float* __restrict__ w1t,
                                                    float* __restrict__ h1) {
    __shared__ __align__(16) float xs[128][136];
    __shared__ __align__(16) float wt[64][136];
    int tid = threadIdx.x;
    int m0 = blockIdx.x * 128;
    for (int i = tid; i < 64 * 34; i += 256) {           // stage W^T (swizzled words 0..31)
        int rr = i / 34, w = i - rr * 34;
        float4 v = *(const float4*)&w1t[(size_t)rr * 136 + w * 4];
        int ws = (w < 32) ? (w ^ ((rr >> 3) & 7)) : w;
        *(float4*)&wt[rr][ws * 4] = v;
    }
    for (int i = tid; i < 128 * 32; i += 256) {          // stage emb words 0..31 (swizzled)
        int r = i >> 5, c4 = i & 31;
        int m = m0 + r;
        float4 v = make_float4(0.f, 0.f, 0.f, 0.f);
        if (m < NN) v = *(const float4*)&emb[(size_t)m * EMB + c4 * 4];
        *(float4*)&xs[r][(c4 ^ ((r >> 2) & 7)) * 4] = v;
    }
    for (int i = tid; i < 128 * 8; i += 256) {           // words 32..33: coords+temporal+pad
        int r = i >> 3, c = i & 7;
        int m = m0 + r;
        float v = 0.0f;
        if (m < NN) {
            if (c < 2) v = coords[2 * m + c];
            else if (c < 6) v = temporal[4 * m + (c - 2)];
        }
        xs[r][128 + c] = v;
    }
    __syncthreads();
    int mt = tid >> 3, ot = tid & 7;
    int xswz = mt & 7, wswz = ot & 7;
    float acc[4][8];
#pragma unroll
    for (int mi = 0; mi < 4; ++mi)
#pragma unroll
        for (int oi = 0; oi < 8; ++oi) acc[mi][oi] = 0.0f;
    for (int k4 = 0; k4 < 34; ++k4) {
        int xk = (k4 < 32) ? (k4 ^ xswz) : k4;
        int wk = (k4 < 32) ? (k4 ^ wswz) : k4;
        float4 xv[4], wv[8];
#pragma unroll
        for (int mi = 0; mi < 4; ++mi) xv[mi] = *(const float4*)&xs[mt * 4 + mi][xk * 4];
#pragma unroll
        for (int oi = 0; oi < 8; ++oi) wv[oi] = *(const float4*)&wt[ot * 8 + oi][wk * 4];
#pragma unroll
        for (int mi = 0; mi < 4; ++mi)
#pragma unroll
            for (int oi = 0; oi < 8; ++oi)
                acc[mi][oi] += xv[mi].x * wv[oi].x + xv[mi].y * wv[oi].y
                             + xv[mi].z * wv[oi].z + xv[mi].w * wv[oi].w;
    }
#pragma unroll
    for (int mi = 0; mi < 4; ++mi) {
        int m = m0 + mt * 4 + mi;
        if (m >= NN) continue;
        int ob = ot * 8;
        *(float4*)&h1[(size_t)m * GH + ob] = make_float4(acc[mi][0], acc[mi][1], acc[mi][2], acc[mi][3]);
        *(float4*)&h1[(size_t)m * GH + ob + 4] = make_float4(acc[mi][4], acc[mi][5], acc[mi][6], acc[mi][7]);
    }
}

// ---------------- symmetric-norm aggregation (CSR, int2 edges) ----------------
__global__ __launch_bounds__(256) void agg_kernel(const float* __restrict__ hin,
                                                  const int* __restrict__ rs,
                                                  const int2* __restrict__ ssrcw,
                                                  const float* __restrict__ dinv,
                                                  const float* __restrict__ bias, int relu,
                                                  float* __restrict__ hout) {
    int lane = threadIdx.x & 63;
    int wid = threadIdx.x >> 6;
    int n = blockIdx.x * 4 + wid;
    if (n >= NN) return;
    float dv = dinv[n];
    float acc = hin[(size_t)n * GH + lane] * (dv * dv);  // self loop
    int2 range = *(const int2*)&rs[n];
    int i = range.x, e1 = range.y;
    for (; i + 7 < e1; i += 8) {
        int4 p0 = *(const int4*)&ssrcw[i];
        int4 p1 = *(const int4*)&ssrcw[i + 2];
        int4 p2 = *(const int4*)&ssrcw[i + 4];
        int4 p3 = *(const int4*)&ssrcw[i + 6];
        float a0 = hin[(size_t)p0.x * GH + lane];
        float a1 = hin[(size_t)p0.z * GH + lane];
        float a2 = hin[(size_t)p1.x * GH + lane];
        float a3 = hin[(size_t)p1.z * GH + lane];
        float a4 = hin[(size_t)p2.x * GH + lane];
        float a5 = hin[(size_t)p2.z * GH + lane];
        float a6 = hin[(size_t)p3.x * GH + lane];
        float a7 = hin[(size_t)p3.z * GH + lane];
        acc += a0 * __int_as_float(p0.y) + a1 * __int_as_float(p0.w)
             + a2 * __int_as_float(p1.y) + a3 * __int_as_float(p1.w)
             + a4 * __int_as_float(p2.y) + a5 * __int_as_float(p2.w)
             + a6 * __int_as_float(p3.y) + a7 * __int_as_float(p3.w);
    }
    for (; i + 3 < e1; i += 4) {
        int4 p0 = *(const int4*)&ssrcw[i];
        int4 p1 = *(const int4*)&ssrcw[i + 2];
        float a0 = hin[(size_t)p0.x * GH + lane];
        float a1 = hin[(size_t)p0.z * GH + lane];
        float a2 = hin[(size_t)p1.x * GH + lane];
        float a3 = hin[(size_t)p1.z * GH + lane];
        acc += a0 * __int_as_float(p0.y) + a1 * __int_as_float(p0.w)
             + a2 * __int_as_float(p1.y) + a3 * __int_as_float(p1.w);
    }
    for (; i < e1; ++i) {
        int2 p = ssrcw[i];
        acc += hin[(size_t)p.x * GH + lane] * __int_as_float(p.y);
    }
    if (bias) acc += bias[lane];
    if (relu) acc = fmaxf(acc, 0.0f);
    hout[(size_t)n * GH + lane] = acc;
}

// ---------------- pre-GEMM v5: K=64 via Wcomb, gather fused ----------------
__global__ __launch_bounds__(256) void pregemm_kernel(const float* __restrict__ a2,
                                                      const int* __restrict__ seq,
                                                      const float* __restrict__ wcomb,
                                                      const float* __restrict__ bcomb,
                                                      const int* __restrict__ lengths,
                                                      float* __restrict__ xpf,
                                                      float* __restrict__ xpb) {
    int dir = blockIdx.z;
    int o0 = blockIdx.y * PO;
    int m0 = blockIdx.x * PM;
    const float* wc = wcomb + (size_t)dir * G4 * GH;
    __shared__ __align__(16) float xs[PM][GH];   // 32KB
    __shared__ __align__(16) float ws[PO][GH];   // 32KB
    __shared__ float bsh[PO];
    int tid = threadIdx.x;
#pragma unroll
    for (int i = 0; i < 8; ++i) {          // stage Wcomb rows (swizzled)
        int idx = i * 256 + tid;
        int row = idx >> 4, c4 = idx & 15;
        float4 v = *(const float4*)&wc[(size_t)(o0 + row) * GH + c4 * 4];
        *(float4*)&ws[row][(c4 ^ ((row >> 3) & 7)) * 4] = v;
    }
    if (tid < PO) bsh[tid] = bcomb[dir * G4 + o0 + tid];
#pragma unroll
    for (int i = 0; i < 8; ++i) {          // stage a2 via fused gather (swizzled)
        int idx = i * 256 + tid;
        int r = idx >> 4, c4 = idx & 15;
        int m = m0 + r;
        int t = m >> 6, b = m & 63;
        int tsrc = t;
        if (dir) { int len = lengths[b]; tsrc = (t < len) ? (len - 1 - t) : t; }
        int node = seq[b * TT + tsrc];
        float4 v = *(const float4*)&a2[(size_t)node * GH + c4 * 4];
        *(float4*)&xs[r][(c4 ^ ((r >> 3) & 3)) * 4] = v;
    }
    __syncthreads();
    int mt = tid >> 4, ot = tid & 15;
    int mswz = mt & 3, oswz = ot & 7;
    float acc[8][8];
#pragma unroll
    for (int mi = 0; mi < 8; ++mi)
#pragma unroll
        for (int oi = 0; oi < 8; ++oi) acc[mi][oi] = 0.0f;
    for (int k4 = 0; k4 < 16; ++k4) {
        int xk = (k4 ^ mswz) * 4;
        int wk = (k4 ^ oswz) * 4;
        float4 xv[8], wv[8];
#pragma unroll
        for (int mi = 0; mi < 8; ++mi) xv[mi] = *(const float4*)&xs[mt * 8 + mi][xk];
#pragma unroll
        for (int oi = 0; oi < 8; ++oi) wv[oi] = *(const float4*)&ws[ot * 8 + oi][wk];
#pragma unroll
        for (int mi = 0; mi < 8; ++mi)
#pragma unroll
            for (int oi = 0; oi < 8; ++oi)
                acc[mi][oi] += xv[mi].x * wv[oi].x + xv[mi].y * wv[oi].y
                             + xv[mi].z * wv[oi].z + xv[mi].w * wv[oi].w;
    }
    float* xp = dir ? xpb : xpf;
#pragma unroll
    for (int mi = 0; mi < 8; ++mi) {
        int m = m0 + mt * 8 + mi;
        int ob = ot * 8;
        float4 oa = make_float4(acc[mi][0] + bsh[ob + 0], acc[mi][1] + bsh[ob + 1],
                                acc[mi][2] + bsh[ob + 2], acc[mi][3] + bsh[ob + 3]);
        float4 obv = make_float4(acc[mi][4] + bsh[ob + 4], acc[mi][5] + bsh[ob + 5],
                                 acc[mi][6] + bsh[ob + 6], acc[mi][7] + bsh[ob + 7]);
        *(float4*)&xp[(size_t)m * G4 + o0 + ob] = oa;
        *(float4*)&xp[(size_t)m * G4 + o0 + ob + 4] = obv;
    }
}

// ---------------- LSTM recurrence v10: ONE barrier/step + parallel phase B ----------------
// Six micro-fix rounds all pinned the old skeleton (2 barriers + 2-wave serial
// phase B) at 175-185us. v10 keeps phase A's mapping (u=(w&1)*64+lane,
// kq=w>>1) but re-maps phase B so WAVE w produces exactly the h-slice
// [kq*16,kq*16+16) it consumes in phase A: waves 2s,2s+1 redundantly compute
// units [16s,16s+16) (private per-wave h,c copies - bitwise identical), so the
// h exchange is WITHIN-WAVE (lgkmcnt, no barrier). Only the partial exchange
// needs the one __syncthreads. part[] double-buffered by t&1 (A(t+1) writes
// may otherwise race stragglers reading B(t)); [u][33] pad -> all LDS <=2-way.
// Phase B: lane = unit*4+gate, 64 lanes x 16 waves fully parallel (1 reduction
// + 1 transcendental each). x loads: 1 scalar/lane/step (was 4).
#define PIN4(v) asm volatile("" : "+v"(v.x), "+v"(v.y), "+v"(v.z), "+v"(v.w))
__global__ __launch_bounds__(1024, 4) void lstm_kernel(const float* __restrict__ xpf,
                                                       const float* __restrict__ xpb,
                                                       const float* __restrict__ w_hh_f,
                                                       const float* __restrict__ w_hh_b,
                                                       const int* __restrict__ lengths,
                                                       float* __restrict__ hfo,
                                                       float* __restrict__ hbo) {
    int chain = blockIdx.x;
    int dir = chain & 1, b = chain >> 1;
    const float* w_hh = dir ? w_hh_b : w_hh_f;
    const float* xp = dir ? xpb : xpf;
    float* ho = dir ? hbo : hfo;
    int tid = threadIdx.x;
    int w = tid >> 6, lane = tid & 63;
    int u = tid & 127;            // phase A unit
    int kq = tid >> 7;            // phase A k-slice (= w>>1)
    int uu = lane >> 2, g = lane & 3;
    int x = (w >> 1) * 16 + uu;   // phase B unit (slice == kq)
    int len = lengths[b];

    float4 W[4][4];
#pragma unroll
    for (int gg = 0; gg < 4; ++gg)
#pragma unroll
        for (int j4 = 0; j4 < 4; ++j4) {
            W[gg][j4] = *(const float4*)&w_hh[(size_t)(gg * HH + u) * HH + kq * 16 + j4 * 4];
            PIN4(W[gg][j4]);
        }

    __shared__ __align__(16) float part[2][128][33];  // [buf][u][g*8+kq, pad]
    __shared__ __align__(16) float hlw[16][16];       // per-wave private h slice
    __shared__ __align__(16) float actw[16][16][4];   // per-wave act exchange
    if (lane < 16) hlw[w][lane] = 0.0f;
    __syncthreads();

    float cst = 0.0f, hkeep = 0.0f;
    int tprev = -1;
    bool hwriter = ((w & 1) == 0) && (g == 0);
    const float* xbase = xp + (size_t)b * G4 + g * HH + x;
    float xcur = xbase[0];
    for (int t = 0; t < len; ++t) {
        // deferred global h store + next-x prefetch (covered by phase A)
        if (hwriter && tprev >= 0) ho[((size_t)b * TT + tprev) * HH + x] = hkeep;
        float xnext = (t + 1 < len) ? xbase[(size_t)(t + 1) * (BB * G4)] : 0.0f;
        // ---- phase A: wave-uniform h broadcast from OWN slice ----
        const float4* h4 = (const float4*)&hlw[w][0];
        float a0 = 0.f, a1 = 0.f, a2 = 0.f, a3 = 0.f;
#pragma unroll
        for (int j4 = 0; j4 < 4; ++j4) {
            float4 hv = h4[j4];
            a0 += W[0][j4].x * hv.x + W[0][j4].y * hv.y + W[0][j4].z * hv.z + W[0][j4].w * hv.w;
            a1 += W[1][j4].x * hv.x + W[1][j4].y * hv.y + W[1][j4].z * hv.z + W[1][j4].w * hv.w;
            a2 += W[2][j4].x * hv.x + W[2][j4].y * hv.y + W[2][j4].z * hv.z + W[2][j4].w * hv.w;
            a3 += W[3][j4].x * hv.x + W[3][j4].y * hv.y + W[3][j4].z * hv.z + W[3][j4].w * hv.w;
        }
        float* pw = &part[t & 1][u][kq];
        pw[0]  = a0;
        pw[8]  = a1;
        pw[16] = a2;
        pw[24] = a3;
        __syncthreads();          // the ONE barrier per step
        // ---- phase B: lane = (uu,g); all 16 waves, 2x redundant per slice ----
        const float4* pr = (const float4*)&part[t & 1][x][g * 8];
        float4 q0 = pr[0], q1 = pr[1];
        float s = ((q0.x + q0.y) + (q0.z + q0.w)) + ((q1.x + q1.y) + (q1.z + q1.w)) + xcur;
        float act = (g == 2) ? tanhf_(s) : sigf(s);
        actw[w][uu][g] = act;
        asm volatile("s_waitcnt lgkmcnt(0)" ::: "memory");
        float4 av = *(const float4*)&actw[w][uu][0];   // i,f,g,o
        cst = av.y * cst + av.x * av.z;
        float h = av.w * tanhf_(cst);
        if (g == 0) hlw[w][uu] = h;
        asm volatile("s_waitcnt lgkmcnt(0)" ::: "memory");
        hkeep = h;
        tprev = dir ? (len - 1 - t) : t;
        xcur = xnext;
    }
    if (hwriter && tprev >= 0) ho[((size_t)b * TT + tprev) * HH + x] = hkeep;
}

// ---------------- masked attention pooling ----------------
__global__ __launch_bounds__(256) void attn_kernel(const float* __restrict__ hf,
                                                   const float* __restrict__ hb,
                                                   const float* __restrict__ attn_w,
                                                   const float* __restrict__ attn_b,
                                                   const int* __restrict__ lengths,
                                                   float* __restrict__ ctx) {
    int b = blockIdx.x;
    int tid = threadIdx.x;
    int len = lengths[b];
    __shared__ __align__(16) float wl[256];
    __shared__ float pl[256];
    __shared__ float red[256];
    wl[tid] = attn_w[tid];
    __syncthreads();
    float sc = -3.0e38f;
    if (tid < len) {
        const float4* rf = (const float4*)(hf + ((size_t)b * TT + tid) * HH);
        const float4* rb = (const float4*)(hb + ((size_t)b * TT + tid) * HH);
        const float4* w4 = (const float4*)wl;
        float s = attn_b[0];
        for (int k4 = 0; k4 < 32; ++k4) {
            float4 a = rf[k4], ww = w4[k4];
            s += a.x * ww.x + a.y * ww.y + a.z * ww.z + a.w * ww.w;
        }
        for (int k4 = 0; k4 < 32; ++k4) {
            float4 a = rb[k4], ww = w4[32 + k4];
            s += a.x * ww.x + a.y * ww.y + a.z * ww.z + a.w * ww.w;
        }
        sc = s;
    }
    red[tid] = sc;
    __syncthreads();
    for (int off = 128; off > 0; off >>= 1) {
        if (tid < off) red[tid] = fmaxf(red[tid], red[tid + off]);
        __syncthreads();
    }
    float mx = red[0];
    __syncthreads();
    float e = (tid < len) ? __expf(sc - mx) : 0.0f;
    red[tid] = e;
    __syncthreads();
    for (int off = 128; off > 0; off >>= 1) {
        if (tid < off) red[tid] += red[tid + off];
        __syncthreads();
    }
    float inv = 1.0f / red[0];
    pl[tid] = e * inv;
    __syncthreads();
    float acc = 0.0f;
    const float* basep = (tid < HH) ? (hf + (size_t)b * TT * HH + tid)
                                    : (hb + (size_t)b * TT * HH + (tid - HH));
#pragma unroll 4
    for (int t = 0; t < len; ++t) acc += pl[t] * basep[(size_t)t * HH];
    ctx[(size_t)b * 256 + tid] = acc;
}

// ---------------- final FC v2: thread = 4 n-cols x 16 b-rows ----------------
__global__ __launch_bounds__(256) void fc_kernel(const float* __restrict__ ctx,
                                                 const float* __restrict__ fc_w,
                                                 const float* __restrict__ fc_b,
                                                 float* __restrict__ out) {
    __shared__ __align__(16) float cl[64][256];
    for (int i = threadIdx.x; i < 64 * 256 / 4; i += 256)
        ((float4*)cl)[i] = ((const float4*)ctx)[i];
    __syncthreads();
    int lane = threadIdx.x & 63;
    int bq = threadIdx.x >> 6;
    int nb = blockIdx.x * 256 + lane;
    float acc[16][4];
#pragma unroll
    for (int i = 0; i < 16; ++i)
#pragma unroll
        for (int c = 0; c < 4; ++c) acc[i][c] = 0.0f;
    for (int k4 = 0; k4 < 64; ++k4) {
        int k = k4 * 4;
        float w[4][4];
#pragma unroll
        for (int j = 0; j < 4; ++j)
#pragma unroll
            for (int c = 0; c < 4; ++c) {
                int n = nb + c * 64;
                w[j][c] = (n < NN) ? fc_w[(size_t)(k + j) * NN + n] : 0.0f;
            }
#pragma unroll
        for (int i = 0; i < 16; ++i) {
            float4 cv = *(const float4*)&cl[bq * 16 + i][k];
#pragma unroll
            for (int c = 0; c < 4; ++c)
                acc[i][c] += cv.x * w[0][c] + cv.y * w[1][c] + cv.z * w[2][c] + cv.w * w[3][c];
        }
    }
#pragma unroll
    for (int i = 0; i < 16; ++i)
#pragma unroll
        for (int c = 0; c < 4; ++c) {
            int n = nb + c * 64;
            if (n < NN) out[(size_t)(bq * 16 + i) * NN + n] = acc[i][c] + fc_b[n];
        }
}

// ---------------- host launcher ----------------
extern "C" void kernel_launch(void* const* d_in, const int* in_sizes, int n_in,
                              void* d_out, int out_size, void* d_ws, size_t ws_size,
                              hipStream_t stream) {
    const float* x_coords   = (const float*)d_in[0];
    const float* temporal   = (const float*)d_in[1];
    const int*   edge_index = (const int*)d_in[2];
    const float* edge_w     = (const float*)d_in[3];
    const int*   seq        = (const int*)d_in[4];
    const int*   lengths    = (const int*)d_in[5];
    const float* node_emb   = (const float*)d_in[6];
    const float* gcn1_w     = (const float*)d_in[7];
    const float* gcn1_b     = (const float*)d_in[8];
    const float* gcn2_w     = (const float*)d_in[9];
    const float* gcn2_b     = (const float*)d_in[10];
    const float* w_ih_f     = (const float*)d_in[11];
    const float* w_hh_f     = (const float*)d_in[12];
    const float* b_ih_f     = (const float*)d_in[13];
    const float* b_hh_f     = (const float*)d_in[14];
    const float* w_ih_b     = (const float*)d_in[15];
    const float* w_hh_b     = (const float*)d_in[16];
    const float* b_ih_b     = (const float*)d_in[17];
    const float* b_hh_b     = (const float*)d_in[18];
    const float* attn_w     = (const float*)d_in[19];
    const float* attn_b     = (const float*)d_in[20];
    const float* fc_w       = (const float*)d_in[21];
    const float* fc_b       = (const float*)d_in[22];
    float* out = (float*)d_out;

    char* base = (char*)d_ws;
    size_t off = 0;
    auto alloc = [&](size_t nbytes) -> void* {
        void* p = base + off;
        off = (off + nbytes + 255) & ~(size_t)255;
        return p;
    };
    int*   cnt     = (int*)alloc((size_t)2 * NN * 4);  // cnt + degw contiguous (one memset)
    float* degw    = (float*)(cnt + NN);
    float* dinv    = (float*)alloc((size_t)NN * 4);
    int*   rs      = (int*)alloc(((size_t)NN + 1) * 4);
    int*   cursor  = (int*)alloc((size_t)NN * 4);
    int*   partials= (int*)alloc(64 * 4);
    int2*  ssrcw   = (int2*)alloc((size_t)NE * 8);
    float* h1      = (float*)alloc((size_t)NN * GH * 4);
    float* z1      = (float*)alloc((size_t)NN * GH * 4);
    float* a2      = h1;  // h1 dead after agg1
    float* w1t     = (float*)alloc((size_t)64 * 136 * 4);
    float* wcomb   = (float*)alloc((size_t)2 * G4 * GH * 4);
    float* bcomb   = (float*)alloc((size_t)2 * G4 * 4);
    float* xpf     = (float*)alloc((size_t)TT * BB * G4 * 4);
    float* xpb     = (float*)alloc((size_t)TT * BB * G4 * 4);
    float* hfo     = (float*)alloc((size_t)BB * TT * HH * 4);
    float* hbo     = (float*)alloc((size_t)BB * TT * HH * 4);
    float* ctx     = (float*)alloc((size_t)BB * 256 * 4);
    (void)ws_size; (void)in_sizes; (void)n_in; (void)out_size;

    hipMemsetAsync(cnt, 0, (size_t)2 * NN * 4, stream);

    hist_kernel<<<(NE + 255) / 256, 256, 0, stream>>>(edge_index, edge_w, cnt, degw);
    const int nblk = (NN + 1023) / 1024;  // 49
    scan1_kernel<<<nblk, 1024, 0, stream>>>(cnt, degw, dinv, rs, partials);
    misc_kernel<<<35, 256, 0, stream>>>(partials, nblk, gcn1_w, w1t);
    wcomb_kernel<<<256, 256, 0, stream>>>(w_ih_f, w_ih_b, gcn2_w, gcn2_b,
                                          b_ih_f, b_hh_f, b_ih_b, b_hh_b, wcomb, bcomb);
    scan3_kernel<<<nblk, 1024, 0, stream>>>(partials, rs, cursor);
    fill_kernel<<<(NE + 255) / 256, 256, 0, stream>>>(edge_index, edge_w, dinv, cursor, ssrcw);

    gemm1_kernel<<<(NN + 127) / 128, 256, 0, stream>>>(x_coords, temporal, node_emb, w1t, h1);
    agg_kernel<<<(NN + 3) / 4, 256, 0, stream>>>(h1, rs, ssrcw, dinv, gcn1_b, 1, z1);
    agg_kernel<<<(NN + 3) / 4, 256, 0, stream>>>(z1, rs, ssrcw, dinv, (const float*)nullptr, 0, a2);

    pregemm_kernel<<<dim3(TT * BB / PM, G4 / PO, 2), 256, 0, stream>>>(
        a2, seq, wcomb, bcomb, lengths, xpf, xpb);
    lstm_kernel<<<BB * 2, 1024, 0, stream>>>(xpf, xpb, w_hh_f, w_hh_b, lengths, hfo, hbo);
    attn_kernel<<<BB, 256, 0, stream>>>(hfo, hbo, attn_w, attn_b, lengths, ctx);
    fc_kernel<<<(NN + 255) / 256, 256, 0, stream>>>(ctx, fc_w, fc_b, out);
}

// Round 15
// 571.153 us; speedup vs baseline: 1.3083x; 1.3083x over previous
//
#include <hip/hip_runtime.h>
#include <math.h>

#define NN 50000
#define NE 800000
#define EMB 128
#define GH 64
#define BB 64
#define TT 200
#define HH 128
#define G4 512
#define IND 134
#define PM 128
#define PO 128

__device__ __forceinline__ float sigf(float x) { return 1.0f / (1.0f + __expf(-x)); }
__device__ __forceinline__ float tanhf_(float x) { return 1.0f - 2.0f / (__expf(2.0f * x) + 1.0f); }

// ---------------- CSR build ----------------
__global__ void hist_kernel(const int* __restrict__ ei, const float* __restrict__ ew,
                            int* __restrict__ cnt, float* __restrict__ degw) {
    int e = blockIdx.x * 256 + threadIdx.x;
    if (e >= NE) return;
    int d = ei[NE + e];
    atomicAdd(&cnt[d], 1);
    atomicAdd(&degw[d], ew[e]);
}

// scan1 + dinv fused (both depend only on hist)
__global__ __launch_bounds__(1024) void scan1_kernel(const int* __restrict__ cnt,
                                                     const float* __restrict__ degw,
                                                     float* __restrict__ dinv,
                                                     int* __restrict__ rs, int* __restrict__ partials) {
    __shared__ int s[1024];
    int gid = blockIdx.x * 1024 + threadIdx.x;
    int v = (gid < NN) ? cnt[gid] : 0;
    if (gid < NN) dinv[gid] = rsqrtf(degw[gid] + 1.0f);   // +1 self loop
    s[threadIdx.x] = v;
    __syncthreads();
    for (int off = 1; off < 1024; off <<= 1) {
        int add = (threadIdx.x >= (unsigned)off) ? s[threadIdx.x - off] : 0;
        __syncthreads();
        s[threadIdx.x] += add;
        __syncthreads();
    }
    if (gid < NN) rs[gid] = s[threadIdx.x] - v;  // exclusive
    if (threadIdx.x == 1023) partials[blockIdx.x] = s[1023];
}

// misc: block 0 = parallel scan of partials; blocks 1..34 = W1 transpose+reorder.
__global__ void misc_kernel(int* __restrict__ partials, int nblk,
                            const float* __restrict__ W1, float* __restrict__ w1t) {
    int blk = blockIdx.x;
    int tid = threadIdx.x;
    if (blk == 0) {
        __shared__ int s[64];
        int v = (tid < nblk) ? partials[tid] : 0;
        s[tid] = v;
        __syncthreads();
        for (int off = 1; off < 64; off <<= 1) {
            int add = (tid >= off) ? s[tid - off] : 0;
            __syncthreads();
            s[tid] += add;
            __syncthreads();
        }
        if (tid < nblk) partials[tid] = s[tid] - v;  // exclusive
    } else {
        int i = (blk - 1) * 256 + tid;
        if (i < 64 * 136) {
            int o = i / 136, j = i - o * 136;
            float v = 0.0f;
            if (j < 128) v = W1[(size_t)(j + 2) * GH + o];
            else if (j < 130) v = W1[(size_t)(j - 128) * GH + o];
            else if (j < 134) v = W1[(size_t)j * GH + o];
            w1t[i] = v;
        }
    }
}

// wcomb: fold gemm2 into pregemm via associativity.
__global__ __launch_bounds__(256) void wcomb_kernel(const float* __restrict__ w_ih_f,
                                                    const float* __restrict__ w_ih_b,
                                                    const float* __restrict__ W2,
                                                    const float* __restrict__ b2,
                                                    const float* __restrict__ b_ih_f,
                                                    const float* __restrict__ b_hh_f,
                                                    const float* __restrict__ b_ih_b,
                                                    const float* __restrict__ b_hh_b,
                                                    float* __restrict__ wcomb,
                                                    float* __restrict__ bcomb) {
    int bx = blockIdx.x, tid = threadIdx.x;
    int dir = bx >> 7, o0 = (bx & 127) * 4;
    const float* w_ih = dir ? w_ih_b : w_ih_f;
    __shared__ __align__(16) float w2s[GH][EMB];    // 32KB, [k][e]
    __shared__ __align__(16) float wihs[4][EMB];    // 2KB, [oo][e]
    __shared__ __align__(16) float b2s[EMB];
    for (int i = tid; i < GH * EMB / 4; i += 256)
        ((float4*)w2s)[i] = ((const float4*)W2)[i];
    for (int i = tid; i < 4 * EMB / 4; i += 256) {
        int oo = i >> 5, e4 = i & 31;
        ((float4*)wihs)[i] = *(const float4*)&w_ih[(size_t)(o0 + oo) * EMB + e4 * 4];
    }
    if (tid < 32) ((float4*)b2s)[tid] = ((const float4*)b2)[tid];
    __syncthreads();
    int oo = tid >> 6, k = tid & 63;
    float acc = 0.0f;
#pragma unroll 8
    for (int e4 = 0; e4 < 32; ++e4) {
        float4 a = *(const float4*)&wihs[oo][e4 * 4];
        float4 w = *(const float4*)&w2s[k][e4 * 4];
        acc += a.x * w.x + a.y * w.y + a.z * w.z + a.w * w.w;
    }
    wcomb[((size_t)dir * G4 + o0 + oo) * GH + k] = acc;
    if (tid < 4) {
        int o = o0 + tid;
        float s = dir ? (b_ih_b[o] + b_hh_b[o]) : (b_ih_f[o] + b_hh_f[o]);
        for (int e = 0; e < EMB; ++e) s += wihs[tid][e] * b2s[e];
        bcomb[dir * G4 + o] = s;
    }
}

__global__ __launch_bounds__(1024) void scan3_kernel(const int* __restrict__ partials,
                                                     int* __restrict__ rs, int* __restrict__ cursor) {
    int gid = blockIdx.x * 1024 + threadIdx.x;
    if (gid < NN) {
        int v = rs[gid] + partials[gid >> 10];
        rs[gid] = v;
        cursor[gid] = v;
    }
    if (gid == 0) rs[NN] = NE;
}

// fill: (src, weight) packed into int2
__global__ void fill_kernel(const int* __restrict__ ei, const float* __restrict__ ew,
                            const float* __restrict__ dinv, int* __restrict__ cursor,
                            int2* __restrict__ ssrcw) {
    int e = blockIdx.x * 256 + threadIdx.x;
    if (e >= NE) return;
    int s = ei[e], d = ei[NE + e];
    int pos = atomicAdd(&cursor[d], 1);
    ssrcw[pos] = make_int2(s, __float_as_int(ew[e] * dinv[s] * dinv[d]));
}

// ---------------- GCN layer 1 GEMM v2 (134 -> 64), register-tiled ----------------
__global__ __launch_bounds__(256) void gemm1_kernel(const float* __restrict__ coords,
                                                    const float* __restrict__ temporal,
                                                    const float* __restrict__ emb,
                                                    const float* __restrict__ w1t,
                                                    float* __restrict__ h1) {
    __shared__ __align__(16) float xs[128][136];
    __shared__ __align__(16) float wt[64][136];
    int tid = threadIdx.x;
    int m0 = blockIdx.x * 128;
    for (int i = tid; i < 64 * 34; i += 256) {           // stage W^T (swizzled words 0..31)
        int rr = i / 34, w = i - rr * 34;
        float4 v = *(const float4*)&w1t[(size_t)rr * 136 + w * 4];
        int ws = (w < 32) ? (w ^ ((rr >> 3) & 7)) : w;
        *(float4*)&wt[rr][ws * 4] = v;
    }
    for (int i = tid; i < 128 * 32; i += 256) {          // stage emb words 0..31 (swizzled)
        int r = i >> 5, c4 = i & 31;
        int m = m0 + r;
        float4 v = make_float4(0.f, 0.f, 0.f, 0.f);
        if (m < NN) v = *(const float4*)&emb[(size_t)m * EMB + c4 * 4];
        *(float4*)&xs[r][(c4 ^ ((r >> 2) & 7)) * 4] = v;
    }
    for (int i = tid; i < 128 * 8; i += 256) {           // words 32..33: coords+temporal+pad
        int r = i >> 3, c = i & 7;
        int m = m0 + r;
        float v = 0.0f;
        if (m < NN) {
            if (c < 2) v = coords[2 * m + c];
            else if (c < 6) v = temporal[4 * m + (c - 2)];
        }
        xs[r][128 + c] = v;
    }
    __syncthreads();
    int mt = tid >> 3, ot = tid & 7;
    int xswz = mt & 7, wswz = ot & 7;
    float acc[4][8];
#pragma unroll
    for (int mi = 0; mi < 4; ++mi)
#pragma unroll
        for (int oi = 0; oi < 8; ++oi) acc[mi][oi] = 0.0f;
    for (int k4 = 0; k4 < 34; ++k4) {
        int xk = (k4 < 32) ? (k4 ^ xswz) : k4;
        int wk = (k4 < 32) ? (k4 ^ wswz) : k4;
        float4 xv[4], wv[8];
#pragma unroll
        for (int mi = 0; mi < 4; ++mi) xv[mi] = *(const float4*)&xs[mt * 4 + mi][xk * 4];
#pragma unroll
        for (int oi = 0; oi < 8; ++oi) wv[oi] = *(const float4*)&wt[ot * 8 + oi][wk * 4];
#pragma unroll
        for (int mi = 0; mi < 4; ++mi)
#pragma unroll
            for (int oi = 0; oi < 8; ++oi)
                acc[mi][oi] += xv[mi].x * wv[oi].x + xv[mi].y * wv[oi].y
                             + xv[mi].z * wv[oi].z + xv[mi].w * wv[oi].w;
    }
#pragma unroll
    for (int mi = 0; mi < 4; ++mi) {
        int m = m0 + mt * 4 + mi;
        if (m >= NN) continue;
        int ob = ot * 8;
        *(float4*)&h1[(size_t)m * GH + ob] = make_float4(acc[mi][0], acc[mi][1], acc[mi][2], acc[mi][3]);
        *(float4*)&h1[(size_t)m * GH + ob + 4] = make_float4(acc[mi][4], acc[mi][5], acc[mi][6], acc[mi][7]);
    }
}

// ---------------- symmetric-norm aggregation (CSR, int2 edges) ----------------
__global__ __launch_bounds__(256) void agg_kernel(const float* __restrict__ hin,
                                                  const int* __restrict__ rs,
                                                  const int2* __restrict__ ssrcw,
                                                  const float* __restrict__ dinv,
                                                  const float* __restrict__ bias, int relu,
                                                  float* __restrict__ hout) {
    int lane = threadIdx.x & 63;
    int wid = threadIdx.x >> 6;
    int n = blockIdx.x * 4 + wid;
    if (n >= NN) return;
    float dv = dinv[n];
    float acc = hin[(size_t)n * GH + lane] * (dv * dv);  // self loop
    int2 range = *(const int2*)&rs[n];
    int i = range.x, e1 = range.y;
    for (; i + 7 < e1; i += 8) {
        int4 p0 = *(const int4*)&ssrcw[i];
        int4 p1 = *(const int4*)&ssrcw[i + 2];
        int4 p2 = *(const int4*)&ssrcw[i + 4];
        int4 p3 = *(const int4*)&ssrcw[i + 6];
        float a0 = hin[(size_t)p0.x * GH + lane];
        float a1 = hin[(size_t)p0.z * GH + lane];
        float a2 = hin[(size_t)p1.x * GH + lane];
        float a3 = hin[(size_t)p1.z * GH + lane];
        float a4 = hin[(size_t)p2.x * GH + lane];
        float a5 = hin[(size_t)p2.z * GH + lane];
        float a6 = hin[(size_t)p3.x * GH + lane];
        float a7 = hin[(size_t)p3.z * GH + lane];
        acc += a0 * __int_as_float(p0.y) + a1 * __int_as_float(p0.w)
             + a2 * __int_as_float(p1.y) + a3 * __int_as_float(p1.w)
             + a4 * __int_as_float(p2.y) + a5 * __int_as_float(p2.w)
             + a6 * __int_as_float(p3.y) + a7 * __int_as_float(p3.w);
    }
    for (; i + 3 < e1; i += 4) {
        int4 p0 = *(const int4*)&ssrcw[i];
        int4 p1 = *(const int4*)&ssrcw[i + 2];
        float a0 = hin[(size_t)p0.x * GH + lane];
        float a1 = hin[(size_t)p0.z * GH + lane];
        float a2 = hin[(size_t)p1.x * GH + lane];
        float a3 = hin[(size_t)p1.z * GH + lane];
        acc += a0 * __int_as_float(p0.y) + a1 * __int_as_float(p0.w)
             + a2 * __int_as_float(p1.y) + a3 * __int_as_float(p1.w);
    }
    for (; i < e1; ++i) {
        int2 p = ssrcw[i];
        acc += hin[(size_t)p.x * GH + lane] * __int_as_float(p.y);
    }
    if (bias) acc += bias[lane];
    if (relu) acc = fmaxf(acc, 0.0f);
    hout[(size_t)n * GH + lane] = acc;
}

// ---------------- pre-GEMM v5: K=64 via Wcomb, gather fused ----------------
__global__ __launch_bounds__(256) void pregemm_kernel(const float* __restrict__ a2,
                                                      const int* __restrict__ seq,
                                                      const float* __restrict__ wcomb,
                                                      const float* __restrict__ bcomb,
                                                      const int* __restrict__ lengths,
                                                      float* __restrict__ xpf,
                                                      float* __restrict__ xpb) {
    int dir = blockIdx.z;
    int o0 = blockIdx.y * PO;
    int m0 = blockIdx.x * PM;
    const float* wc = wcomb + (size_t)dir * G4 * GH;
    __shared__ __align__(16) float xs[PM][GH];   // 32KB
    __shared__ __align__(16) float ws[PO][GH];   // 32KB
    __shared__ float bsh[PO];
    int tid = threadIdx.x;
#pragma unroll
    for (int i = 0; i < 8; ++i) {          // stage Wcomb rows (swizzled)
        int idx = i * 256 + tid;
        int row = idx >> 4, c4 = idx & 15;
        float4 v = *(const float4*)&wc[(size_t)(o0 + row) * GH + c4 * 4];
        *(float4*)&ws[row][(c4 ^ ((row >> 3) & 7)) * 4] = v;
    }
    if (tid < PO) bsh[tid] = bcomb[dir * G4 + o0 + tid];
#pragma unroll
    for (int i = 0; i < 8; ++i) {          // stage a2 via fused gather (swizzled)
        int idx = i * 256 + tid;
        int r = idx >> 4, c4 = idx & 15;
        int m = m0 + r;
        int t = m >> 6, b = m & 63;
        int tsrc = t;
        if (dir) { int len = lengths[b]; tsrc = (t < len) ? (len - 1 - t) : t; }
        int node = seq[b * TT + tsrc];
        float4 v = *(const float4*)&a2[(size_t)node * GH + c4 * 4];
        *(float4*)&xs[r][(c4 ^ ((r >> 3) & 3)) * 4] = v;
    }
    __syncthreads();
    int mt = tid >> 4, ot = tid & 15;
    int mswz = mt & 3, oswz = ot & 7;
    float acc[8][8];
#pragma unroll
    for (int mi = 0; mi < 8; ++mi)
#pragma unroll
        for (int oi = 0; oi < 8; ++oi) acc[mi][oi] = 0.0f;
    for (int k4 = 0; k4 < 16; ++k4) {
        int xk = (k4 ^ mswz) * 4;
        int wk = (k4 ^ oswz) * 4;
        float4 xv[8], wv[8];
#pragma unroll
        for (int mi = 0; mi < 8; ++mi) xv[mi] = *(const float4*)&xs[mt * 8 + mi][xk];
#pragma unroll
        for (int oi = 0; oi < 8; ++oi) wv[oi] = *(const float4*)&ws[ot * 8 + oi][wk];
#pragma unroll
        for (int mi = 0; mi < 8; ++mi)
#pragma unroll
            for (int oi = 0; oi < 8; ++oi)
                acc[mi][oi] += xv[mi].x * wv[oi].x + xv[mi].y * wv[oi].y
                             + xv[mi].z * wv[oi].z + xv[mi].w * wv[oi].w;
    }
    float* xp = dir ? xpb : xpf;
#pragma unroll
    for (int mi = 0; mi < 8; ++mi) {
        int m = m0 + mt * 8 + mi;
        int ob = ot * 8;
        float4 oa = make_float4(acc[mi][0] + bsh[ob + 0], acc[mi][1] + bsh[ob + 1],
                                acc[mi][2] + bsh[ob + 2], acc[mi][3] + bsh[ob + 3]);
        float4 obv = make_float4(acc[mi][4] + bsh[ob + 4], acc[mi][5] + bsh[ob + 5],
                                 acc[mi][6] + bsh[ob + 6], acc[mi][7] + bsh[ob + 7]);
        *(float4*)&xp[(size_t)m * G4 + o0 + ob] = oa;
        *(float4*)&xp[(size_t)m * G4 + o0 + ob + 4] = obv;
    }
}

// ---------------- LSTM recurrence v9 (structure Z; DVFS-latency floor ~175us) ----------------
// R14 lesson: v10's one-barrier redesign (per-lane scalar LDS exchanges + 2
// serial lgkmcnt(0) waits) doubled the time -> reverted. All seven structural
// variants land at 175-185us = ~0.88us/step; at the reduced DVFS clock implied
// by 13% VALUBusy on half the CUs, the modeled ~1100-1300cyc serial chain
// matches measurement. This is the recurrence's structural floor; frozen.
#define PIN4(v) asm volatile("" : "+v"(v.x), "+v"(v.y), "+v"(v.z), "+v"(v.w))
__global__ __launch_bounds__(1024, 4) void lstm_kernel(const float* __restrict__ xpf,
                                                       const float* __restrict__ xpb,
                                                       const float* __restrict__ w_hh_f,
                                                       const float* __restrict__ w_hh_b,
                                                       const int* __restrict__ lengths,
                                                       float* __restrict__ hfo,
                                                       float* __restrict__ hbo) {
    int chain = blockIdx.x;
    int dir = chain & 1, b = chain >> 1;
    const float* w_hh = dir ? w_hh_b : w_hh_f;
    const float* xp = dir ? xpb : xpf;
    float* ho = dir ? hbo : hfo;
    int tid = threadIdx.x;
    int u = tid & 127;
    int kq = tid >> 7;    // 0..7
    int len = lengths[b];

    float4 W[4][4];
#pragma unroll
    for (int g = 0; g < 4; ++g)
#pragma unroll
        for (int j4 = 0; j4 < 4; ++j4) {
            W[g][j4] = *(const float4*)&w_hh[(size_t)(g * HH + u) * HH + kq * 16 + j4 * 4];
            PIN4(W[g][j4]);
        }

    __shared__ __align__(16) float hl[HH];
    __shared__ __align__(16) float part[8][HH][4];   // [kq][u][gate]
    if (tid < HH) hl[tid] = 0.0f;
    __syncthreads();

    float cst = 0.0f, hkeep = 0.0f;
    int tprev = -1;
    float x0 = 0.f, x1 = 0.f, x2 = 0.f, x3 = 0.f;
    const float* xpt = xp + (size_t)b * G4 + u;
    if (tid < HH && len > 0) {
        x0 = xpt[0]; x1 = xpt[HH]; x2 = xpt[2 * HH]; x3 = xpt[3 * HH];
    }
    for (int t = 0; t < len; ++t) {
        float n0 = 0.f, n1 = 0.f, n2 = 0.f, n3 = 0.f;
        if (tid < HH) {
            if (tprev >= 0) ho[((size_t)b * TT + tprev) * HH + u] = hkeep;  // store h(t-1)
            if (t + 1 < len) {                                             // prefetch x(t+1)
                const float* xn = xpt + (size_t)(t + 1) * (BB * G4);
                n0 = xn[0]; n1 = xn[HH]; n2 = xn[2 * HH]; n3 = xn[3 * HH];
            }
        }
        // phase A: all 16 waves; wave-uniform h broadcast reads
        const float4* h4 = (const float4*)&hl[kq * 16];
        float a0 = 0.f, a1 = 0.f, a2 = 0.f, a3 = 0.f;
#pragma unroll
        for (int j4 = 0; j4 < 4; ++j4) {
            float4 hv = h4[j4];
            a0 += W[0][j4].x * hv.x + W[0][j4].y * hv.y + W[0][j4].z * hv.z + W[0][j4].w * hv.w;
            a1 += W[1][j4].x * hv.x + W[1][j4].y * hv.y + W[1][j4].z * hv.z + W[1][j4].w * hv.w;
            a2 += W[2][j4].x * hv.x + W[2][j4].y * hv.y + W[2][j4].z * hv.z + W[2][j4].w * hv.w;
            a3 += W[3][j4].x * hv.x + W[3][j4].y * hv.y + W[3][j4].z * hv.z + W[3][j4].w * hv.w;
        }
        if (kq) *(float4*)&part[kq][u][0] = make_float4(a0, a1, a2, a3);
        __syncthreads();
        // phase B: 2 waves (kq=0 threads)
        if (tid < HH) {
            float s0 = x0 + a0, s1 = x1 + a1, s2 = x2 + a2, s3 = x3 + a3;
#pragma unroll
            for (int q = 1; q < 8; ++q) {
                float4 p = *(const float4*)&part[q][u][0];
                s0 += p.x; s1 += p.y; s2 += p.z; s3 += p.w;
            }
            float gi = sigf(s0), gf = sigf(s1), gg = tanhf_(s2), go = sigf(s3);
            cst = gf * cst + gi * gg;
            float h = go * tanhf_(cst);
            hl[u] = h;
            hkeep = h;
            tprev = dir ? (len - 1 - t) : t;
            x0 = n0; x1 = n1; x2 = n2; x3 = n3;
        }
        __syncthreads();
    }
    if (tid < HH && tprev >= 0) ho[((size_t)b * TT + tprev) * HH + u] = hkeep;
}

// ---------------- masked attention pooling ----------------
__global__ __launch_bounds__(256) void attn_kernel(const float* __restrict__ hf,
                                                   const float* __restrict__ hb,
                                                   const float* __restrict__ attn_w,
                                                   const float* __restrict__ attn_b,
                                                   const int* __restrict__ lengths,
                                                   float* __restrict__ ctx) {
    int b = blockIdx.x;
    int tid = threadIdx.x;
    int len = lengths[b];
    __shared__ __align__(16) float wl[256];
    __shared__ float pl[256];
    __shared__ float red[256];
    wl[tid] = attn_w[tid];
    __syncthreads();
    float sc = -3.0e38f;
    if (tid < len) {
        const float4* rf = (const float4*)(hf + ((size_t)b * TT + tid) * HH);
        const float4* rb = (const float4*)(hb + ((size_t)b * TT + tid) * HH);
        const float4* w4 = (const float4*)wl;
        float s = attn_b[0];
        for (int k4 = 0; k4 < 32; ++k4) {
            float4 a = rf[k4], ww = w4[k4];
            s += a.x * ww.x + a.y * ww.y + a.z * ww.z + a.w * ww.w;
        }
        for (int k4 = 0; k4 < 32; ++k4) {
            float4 a = rb[k4], ww = w4[32 + k4];
            s += a.x * ww.x + a.y * ww.y + a.z * ww.z + a.w * ww.w;
        }
        sc = s;
    }
    red[tid] = sc;
    __syncthreads();
    for (int off = 128; off > 0; off >>= 1) {
        if (tid < off) red[tid] = fmaxf(red[tid], red[tid + off]);
        __syncthreads();
    }
    float mx = red[0];
    __syncthreads();
    float e = (tid < len) ? __expf(sc - mx) : 0.0f;
    red[tid] = e;
    __syncthreads();
    for (int off = 128; off > 0; off >>= 1) {
        if (tid < off) red[tid] += red[tid + off];
        __syncthreads();
    }
    float inv = 1.0f / red[0];
    pl[tid] = e * inv;
    __syncthreads();
    float acc = 0.0f;
    const float* basep = (tid < HH) ? (hf + (size_t)b * TT * HH + tid)
                                    : (hb + (size_t)b * TT * HH + (tid - HH));
#pragma unroll 4
    for (int t = 0; t < len; ++t) acc += pl[t] * basep[(size_t)t * HH];
    ctx[(size_t)b * 256 + tid] = acc;
}

// ---------------- final FC v2: thread = 4 n-cols x 16 b-rows ----------------
__global__ __launch_bounds__(256) void fc_kernel(const float* __restrict__ ctx,
                                                 const float* __restrict__ fc_w,
                                                 const float* __restrict__ fc_b,
                                                 float* __restrict__ out) {
    __shared__ __align__(16) float cl[64][256];
    for (int i = threadIdx.x; i < 64 * 256 / 4; i += 256)
        ((float4*)cl)[i] = ((const float4*)ctx)[i];
    __syncthreads();
    int lane = threadIdx.x & 63;
    int bq = threadIdx.x >> 6;
    int nb = blockIdx.x * 256 + lane;
    float acc[16][4];
#pragma unroll
    for (int i = 0; i < 16; ++i)
#pragma unroll
        for (int c = 0; c < 4; ++c) acc[i][c] = 0.0f;
    for (int k4 = 0; k4 < 64; ++k4) {
        int k = k4 * 4;
        float w[4][4];
#pragma unroll
        for (int j = 0; j < 4; ++j)
#pragma unroll
            for (int c = 0; c < 4; ++c) {
                int n = nb + c * 64;
                w[j][c] = (n < NN) ? fc_w[(size_t)(k + j) * NN + n] : 0.0f;
            }
#pragma unroll
        for (int i = 0; i < 16; ++i) {
            float4 cv = *(const float4*)&cl[bq * 16 + i][k];
#pragma unroll
            for (int c = 0; c < 4; ++c)
                acc[i][c] += cv.x * w[0][c] + cv.y * w[1][c] + cv.z * w[2][c] + cv.w * w[3][c];
        }
    }
#pragma unroll
    for (int i = 0; i < 16; ++i)
#pragma unroll
        for (int c = 0; c < 4; ++c) {
            int n = nb + c * 64;
            if (n < NN) out[(size_t)(bq * 16 + i) * NN + n] = acc[i][c] + fc_b[n];
        }
}

// ---------------- host launcher ----------------
extern "C" void kernel_launch(void* const* d_in, const int* in_sizes, int n_in,
                              void* d_out, int out_size, void* d_ws, size_t ws_size,
                              hipStream_t stream) {
    const float* x_coords   = (const float*)d_in[0];
    const float* temporal   = (const float*)d_in[1];
    const int*   edge_index = (const int*)d_in[2];
    const float* edge_w     = (const float*)d_in[3];
    const int*   seq        = (const int*)d_in[4];
    const int*   lengths    = (const int*)d_in[5];
    const float* node_emb   = (const float*)d_in[6];
    const float* gcn1_w     = (const float*)d_in[7];
    const float* gcn1_b     = (const float*)d_in[8];
    const float* gcn2_w     = (const float*)d_in[9];
    const float* gcn2_b     = (const float*)d_in[10];
    const float* w_ih_f     = (const float*)d_in[11];
    const float* w_hh_f     = (const float*)d_in[12];
    const float* b_ih_f     = (const float*)d_in[13];
    const float* b_hh_f     = (const float*)d_in[14];
    const float* w_ih_b     = (const float*)d_in[15];
    const float* w_hh_b     = (const float*)d_in[16];
    const float* b_ih_b     = (const float*)d_in[17];
    const float* b_hh_b     = (const float*)d_in[18];
    const float* attn_w     = (const float*)d_in[19];
    const float* attn_b     = (const float*)d_in[20];
    const float* fc_w       = (const float*)d_in[21];
    const float* fc_b       = (const float*)d_in[22];
    float* out = (float*)d_out;

    char* base = (char*)d_ws;
    size_t off = 0;
    auto alloc = [&](size_t nbytes) -> void* {
        void* p = base + off;
        off = (off + nbytes + 255) & ~(size_t)255;
        return p;
    };
    int*   cnt     = (int*)alloc((size_t)2 * NN * 4);  // cnt + degw contiguous (one memset)
    float* degw    = (float*)(cnt + NN);
    float* dinv    = (float*)alloc((size_t)NN * 4);
    int*   rs      = (int*)alloc(((size_t)NN + 1) * 4);
    int*   cursor  = (int*)alloc((size_t)NN * 4);
    int*   partials= (int*)alloc(64 * 4);
    int2*  ssrcw   = (int2*)alloc((size_t)NE * 8);
    float* h1      = (float*)alloc((size_t)NN * GH * 4);
    float* z1      = (float*)alloc((size_t)NN * GH * 4);
    float* a2      = h1;  // h1 dead after agg1
    float* w1t     = (float*)alloc((size_t)64 * 136 * 4);
    float* wcomb   = (float*)alloc((size_t)2 * G4 * GH * 4);
    float* bcomb   = (float*)alloc((size_t)2 * G4 * 4);
    float* xpf     = (float*)alloc((size_t)TT * BB * G4 * 4);
    float* xpb     = (float*)alloc((size_t)TT * BB * G4 * 4);
    float* hfo     = (float*)alloc((size_t)BB * TT * HH * 4);
    float* hbo     = (float*)alloc((size_t)BB * TT * HH * 4);
    float* ctx     = (float*)alloc((size_t)BB * 256 * 4);
    (void)ws_size; (void)in_sizes; (void)n_in; (void)out_size;

    hipMemsetAsync(cnt, 0, (size_t)2 * NN * 4, stream);

    hist_kernel<<<(NE + 255) / 256, 256, 0, stream>>>(edge_index, edge_w, cnt, degw);
    const int nblk = (NN + 1023) / 1024;  // 49
    scan1_kernel<<<nblk, 1024, 0, stream>>>(cnt, degw, dinv, rs, partials);
    misc_kernel<<<35, 256, 0, stream>>>(partials, nblk, gcn1_w, w1t);
    wcomb_kernel<<<256, 256, 0, stream>>>(w_ih_f, w_ih_b, gcn2_w, gcn2_b,
                                          b_ih_f, b_hh_f, b_ih_b, b_hh_b, wcomb, bcomb);
    scan3_kernel<<<nblk, 1024, 0, stream>>>(partials, rs, cursor);
    fill_kernel<<<(NE + 255) / 256, 256, 0, stream>>>(edge_index, edge_w, dinv, cursor, ssrcw);

    gemm1_kernel<<<(NN + 127) / 128, 256, 0, stream>>>(x_coords, temporal, node_emb, w1t, h1);
    agg_kernel<<<(NN + 3) / 4, 256, 0, stream>>>(h1, rs, ssrcw, dinv, gcn1_b, 1, z1);
    agg_kernel<<<(NN + 3) / 4, 256, 0, stream>>>(z1, rs, ssrcw, dinv, (const float*)nullptr, 0, a2);

    pregemm_kernel<<<dim3(TT * BB / PM, G4 / PO, 2), 256, 0, stream>>>(
        a2, seq, wcomb, bcomb, lengths, xpf, xpb);
    lstm_kernel<<<BB * 2, 1024, 0, stream>>>(xpf, xpb, w_hh_f, w_hh_b, lengths, hfo, hbo);
    attn_kernel<<<BB, 256, 0, stream>>>(hfo, hbo, attn_w, attn_b, lengths, ctx);
    fc_kernel<<<(NN + 255) / 256, 256, 0, stream>>>(ctx, fc_w, fc_b, out);
}